// Round 8
// baseline (599.434 us; speedup 1.0000x reference)
//
#include <hip/hip_runtime.h>
#include <hip/hip_bf16.h>

// SelfAttention: B=2, S=2048, H=16, D=64, E=1024
// ROUND 8: ledger shows total ~= attn + 125us (invariant over 4 proj / 3
// outproj variants) -> only attn matters. attn occupancy is GRID-limited:
// LDS 37.4KB & VGPR 56 allow 4 blocks/CU (32 waves) but grid 512 gives 2.
// Fix: 64 q-rows per block, grid 1024 = 4 blocks/CU. 8 waves = wq{0,1} x
// wk{0..3}: 32 q-rows x 16-key quarter each. QK unchanged (2 chained K=32
// MFMAs); PV/lsum use K=16 MFMAs consuming pv16 directly (kappa layout gives
// the V fragment as contiguous bf16x4). 4-way combine (2-stage publish).
// Per-CU MFMA/LDS/VALU totals conserved; concurrency doubles (R4 inverse).
// proj/outproj byte-exact R0. ws: Qb[0,8M) Kb[8M,16M) Vt[16M,24M) Og[24M,32M).

#define NHB 16
#define HS  64
#define EMB 1024
#define BB  2
#define SS  2048
#define NT  (SS / 64)

typedef __bf16 bf16_t;
typedef bf16_t bf16x8 __attribute__((ext_vector_type(8)));
typedef bf16_t bf16x4 __attribute__((ext_vector_type(4)));
typedef float  f32x4  __attribute__((ext_vector_type(4)));
typedef short  s16x4  __attribute__((ext_vector_type(4)));

__device__ __forceinline__ f32x4 mfma16(bf16x8 a, bf16x8 b, f32x4 c) {
    return __builtin_amdgcn_mfma_f32_16x16x32_bf16(a, b, c, 0, 0, 0);
}

// 16x16 K=16 bf16 MFMA (A,B = 4 bf16 / 2 VGPRs). Builtin name varies by
// ROCm vintage; guard and fall back to inline asm (ISA: v_mfma_f32_16x16x16_bf16).
__device__ __forceinline__ f32x4 mfma16k16(bf16x4 a, bf16x4 b, f32x4 c) {
#if __has_builtin(__builtin_amdgcn_mfma_f32_16x16x16_bf16)
    return __builtin_amdgcn_mfma_f32_16x16x16_bf16(a, b, c, 0, 0, 0);
#elif __has_builtin(__builtin_amdgcn_mfma_f32_16x16x16bf16_1k)
    return __builtin_amdgcn_mfma_f32_16x16x16bf16_1k(
        __builtin_bit_cast(s16x4, a), __builtin_bit_cast(s16x4, b), c, 0, 0, 0);
#else
    f32x4 d;
    asm("v_mfma_f32_16x16x16_bf16 %0, %1, %2, %3"
        : "=v"(d) : "v"(a), "v"(b), "v"(c));
    return d;
#endif
}

// raw v_exp_f32 (computes 2^x) -- NOT libm exp2f (slow guarded sequence)
__device__ __forceinline__ float fast_exp2(float x) {
#if __has_builtin(__builtin_amdgcn_exp2f)
    return __builtin_amdgcn_exp2f(x);
#else
    float r;
    asm("v_exp_f32 %0, %1" : "=v"(r) : "v"(x));
    return r;
#endif
}

// ---------------------------------------------------------------------------
// Kernel 1: Q/K/V projections — byte-identical to R0 (measured-best config).
// ---------------------------------------------------------------------------
__global__ __launch_bounds__(512) void proj_kernel(
    const float* __restrict__ queries, const float* __restrict__ keys,
    const float* __restrict__ values,
    const float* __restrict__ Wq, const float* __restrict__ Wk,
    const float* __restrict__ Wv,
    bf16_t* __restrict__ Qb, bf16_t* __restrict__ Kb, bf16_t* __restrict__ Vt)
{
    __shared__ bf16_t Ws[3][64][72];
    __shared__ bf16_t Xs[128][72];

    const int tid  = threadIdx.x;
    const int wave = tid >> 6, lane = tid & 63;
    const int q4 = lane >> 4, l16 = lane & 15;
    const int s0 = blockIdx.x * 128;
    const int h  = blockIdx.y, n = blockIdx.z;

    #pragma unroll
    for (int i = 0; i < 6; ++i) {
        int g = i * 512 + tid;
        int mW = g >> 10;                 // uniform per i
        int idx4 = g & 1023;
        const float* wp = (mW == 0) ? Wq : (mW == 1) ? Wk : Wv;
        float4 v = ((const float4*)wp)[idx4];
        int r = idx4 >> 4, c = (idx4 & 15) * 4;
        Ws[mW][r][c+0] = (bf16_t)v.x; Ws[mW][r][c+1] = (bf16_t)v.y;
        Ws[mW][r][c+2] = (bf16_t)v.z; Ws[mW][r][c+3] = (bf16_t)v.w;
    }

    const size_t headBase = (size_t)(n * NHB + h) * SS * HS;

    float4 gx[4];
    auto loadX = [&](const float* xp) {
        #pragma unroll
        for (int i = 0; i < 4; ++i) {
            int idx4 = i * 512 + tid;                 // 2048 chunks: 128 x 16
            int r = idx4 >> 4, c = (idx4 & 15) * 4;
            gx[i] = *(const float4*)&xp[((size_t)(n * SS + s0 + r)) * EMB + h * HS + c];
        }
    };
    loadX(queries);

    for (int p = 0; p < 3; ++p) {
        __syncthreads();
        #pragma unroll
        for (int i = 0; i < 4; ++i) {
            int idx4 = i * 512 + tid;
            int r = idx4 >> 4, c = (idx4 & 15) * 4;
            Xs[r][c+0] = (bf16_t)gx[i].x; Xs[r][c+1] = (bf16_t)gx[i].y;
            Xs[r][c+2] = (bf16_t)gx[i].z; Xs[r][c+3] = (bf16_t)gx[i].w;
        }
        if (p == 0) loadX(keys);
        else if (p == 1) loadX(values);
        __syncthreads();

        bf16x8 xf[2], wf[4][2];
        #pragma unroll
        for (int kk = 0; kk < 2; ++kk)
            xf[kk] = *(const bf16x8*)&Xs[wave * 16 + l16][kk * 32 + q4 * 8];
        #pragma unroll
        for (int ct = 0; ct < 4; ++ct)
            #pragma unroll
            for (int kk = 0; kk < 2; ++kk)
                wf[ct][kk] = *(const bf16x8*)&Ws[p][ct * 16 + l16][kk * 32 + q4 * 8];

        if (p < 2) {
            // sigma gather: phys channel = q4*16 + ct*4 + i -> two 16B stores
            bf16_t* dst = (p == 0) ? Qb : Kb;
            // Q carries log2e/sqrt(EMB) so attn can use raw v_exp_f32 (2^x)
            const float sc = (p == 0) ? (0.03125f * 1.44269504f) : 1.0f;
            bf16x8 lo, hi;
            #pragma unroll
            for (int ct = 0; ct < 4; ++ct) {
                f32x4 acc = {};
                acc = mfma16(wf[ct][0], xf[0], acc);
                acc = mfma16(wf[ct][1], xf[1], acc);
                #pragma unroll
                for (int i = 0; i < 4; ++i) {
                    bf16_t v = (bf16_t)(acc[i] * sc);
                    if (ct < 2) lo[ct * 4 + i] = v;
                    else        hi[(ct - 2) * 4 + i] = v;
                }
            }
            bf16_t* rp = dst + headBase
                + (size_t)(s0 + wave * 16 + l16) * HS + q4 * 16;
            *(bf16x8*)rp = lo;
            *(bf16x8*)(rp + 8) = hi;
        } else {
            #pragma unroll
            for (int ct = 0; ct < 4; ++ct) {
                f32x4 acc = {};
                acc = mfma16(xf[0], wf[ct][0], acc);
                acc = mfma16(xf[1], wf[ct][1], acc);
                bf16x4 pk;
                #pragma unroll
                for (int i = 0; i < 4; ++i) pk[i] = (bf16_t)acc[i];
                *(bf16x4*)&Vt[headBase + (size_t)(ct * 16 + l16) * SS
                              + s0 + (wave >> 1) * 32 + q4 * 8 + (wave & 1) * 4] = pk;
            }
        }
    }
}

// ---------------------------------------------------------------------------
// Kernel 2: flash attention. grid 1024 (XCD-swizzled) x 512 threads,
// 4 blocks/CU (32 waves). Block = 64 q-rows; wave (wq,wk) = 32 q-rows x
// 16-key quarter. QK: K=32 chained pair (as R0). PV/lsum: K=16 MFMAs.
// ---------------------------------------------------------------------------
__global__ __launch_bounds__(512, 8) void attn_kernel(
    const bf16_t* __restrict__ Qb, const bf16_t* __restrict__ Kb,
    const bf16_t* __restrict__ Vt, const int* __restrict__ mask,
    bf16_t* __restrict__ Og)
{
    __shared__ __align__(16) unsigned char smem[37376];
    auto Ks = (bf16_t(*)[64][72])(smem);            // [2][key][d]
    auto Vs = (bf16_t(*)[64][72])(smem + 18432);    // [2][d][kappa-key]
    auto Ms = (float(*)[64])(smem + 36864);         // [2][64] additive bias
    float* fbuf = (float*)smem;                      // combine: 32 KB
    float* lbuf = (float*)(smem + 32768);            // combine: 2 KB

    const int tid = threadIdx.x;
    const int w = tid >> 6, lane = tid & 63;
    const int q4 = lane >> 4, l16 = lane & 15;
    const int wq = w & 1, wk = w >> 1;   // wq: 32-row q block; wk: 16-key quarter

    // XCD swizzle: all 32 q-tiles of a head share an XCD (id%8).
    const int bid = blockIdx.x;
    const int r = bid & 7, t = bid >> 3;      // t 0..127
    const int gi = t >> 5, qt = t & 31;       // gi 0..3, qt 0..31
    const int g = gi * 8 + r;                 // head-group 0..31
    const int h = g & 15, n = g >> 4;

    const size_t headBase = (size_t)(n * NHB + h) * SS * HS;
    const int* mrow = mask + n * SS;

    const int sr = tid >> 3, sc = (tid & 7) * 8;
    const bf16_t* kb_src = Kb + headBase + (size_t)sr * HS + sc;
    const bf16_t* vt_src = Vt + headBase + (size_t)sr * SS + sc;

    bf16x8 bq[2][2];
    #pragma unroll
    for (int st = 0; st < 2; ++st) {
        const bf16_t* qptr = Qb + headBase
            + (size_t)(qt * 64 + wq * 32 + st * 16 + l16) * HS;
        bq[st][0] = *(const bf16x8*)&qptr[q4 * 8];
        bq[st][1] = *(const bf16x8*)&qptr[32 + q4 * 8];
    }

    bf16x4 ones4;
    #pragma unroll
    for (int i = 0; i < 4; ++i) ones4[i] = (bf16_t)1.0f;

    f32x4 oaccT[2][4] = {};
    f32x4 lacc[2] = {};

    *(bf16x8*)&Ks[0][sr][sc] = *(const bf16x8*)kb_src;
    *(bf16x8*)&Vs[0][sr][sc] = *(const bf16x8*)vt_src;
    if (tid < 64) Ms[0][tid] = mrow[tid] ? 0.0f : -3e38f;
    __syncthreads();

    // kappa column base for this wave's 16-key quarter in Vs
    const int vcol = (wk >> 1) * 32 + (wk & 1) * 4 + q4 * 8;

    for (int kt = 0; kt < NT; ++kt) {
        const int cur = kt & 1;
        const bool has_next = (kt + 1) < NT;
        bf16x8 gk, gv; float gm = 0.f;
        if (has_next) {
            const int k0n = (kt + 1) * 64;
            gk = *(const bf16x8*)(kb_src + (size_t)k0n * HS);
            gv = *(const bf16x8*)(vt_src + k0n);
            if (tid < 64) gm = mrow[k0n + tid] ? 0.0f : -3e38f;
        }

        // S^T = bias + K.Q^T over this wave's 16-key quarter
        bf16x8 ak0 = *(const bf16x8*)&Ks[cur][wk * 16 + l16][q4 * 8];
        bf16x8 ak1 = *(const bf16x8*)&Ks[cur][wk * 16 + l16][32 + q4 * 8];
        float4 bias = *(const float4*)&Ms[cur][wk * 16 + q4 * 4];
        f32x4 b4 = {bias.x, bias.y, bias.z, bias.w};
        f32x4 sacc[2];
        __builtin_amdgcn_s_setprio(1);
        #pragma unroll
        for (int st = 0; st < 2; ++st) {
            f32x4 s = mfma16(ak0, bq[st][0], b4);
            sacc[st] = mfma16(ak1, bq[st][1], s);
        }
        __builtin_amdgcn_s_setprio(0);

        // P = 2^S (Q carries log2e/32)
        bf16x4 pv16[2];
        #pragma unroll
        for (int st = 0; st < 2; ++st)
            #pragma unroll
            for (int j = 0; j < 4; ++j)
                pv16[st][j] = (bf16_t)fast_exp2(sacc[st][j]);

        // O^T += V^T.P^T (K=16) ; lsum += ones.P^T
        __builtin_amdgcn_s_setprio(1);
        #pragma unroll
        for (int dt = 0; dt < 4; ++dt) {
            bf16x4 av = *(const bf16x4*)&Vs[cur][dt * 16 + l16][vcol];
            oaccT[0][dt] = mfma16k16(av, pv16[0], oaccT[0][dt]);
            oaccT[1][dt] = mfma16k16(av, pv16[1], oaccT[1][dt]);
        }
        lacc[0] = mfma16k16(ones4, pv16[0], lacc[0]);
        lacc[1] = mfma16k16(ones4, pv16[1], lacc[1]);
        __builtin_amdgcn_s_setprio(0);

        if (has_next) {
            const int nxt = 1 - cur;
            *(bf16x8*)&Ks[nxt][sr][sc] = gk;
            *(bf16x8*)&Vs[nxt][sr][sc] = gv;
            if (tid < 64) Ms[nxt][tid] = gm;
        }
        __syncthreads();
    }

    float ls[2] = {lacc[0][0], lacc[1][0]};

    // 4-way combine across wk, two publish stages (fbuf 32KB reused).
    // Stage A: wk=2 -> col-group wq*2, wk=3 -> wq*2+1.
    if (wk >= 2) {
        const int cg = wq * 2 + (wk - 2);
        #pragma unroll
        for (int st = 0; st < 2; ++st) {
            #pragma unroll
            for (int dt = 0; dt < 4; ++dt)
                #pragma unroll
                for (int j = 0; j < 4; ++j)
                    fbuf[(st * 16 + dt * 4 + j) * 256 + cg * 64 + lane] = oaccT[st][dt][j];
            lbuf[st * 256 + cg * 64 + lane] = ls[st];
        }
    }
    __syncthreads();
    // Stage B: wk=0 absorbs wk=2; wk=1 absorbs wk=3.
    if (wk < 2) {
        const int cg = wq * 2 + wk;
        #pragma unroll
        for (int st = 0; st < 2; ++st) {
            #pragma unroll
            for (int dt = 0; dt < 4; ++dt)
                #pragma unroll
                for (int j = 0; j < 4; ++j)
                    oaccT[st][dt][j] += fbuf[(st * 16 + dt * 4 + j) * 256 + cg * 64 + lane];
            ls[st] += lbuf[st * 256 + cg * 64 + lane];
        }
    }
    __syncthreads();
    // Stage C: wk=1 publishes its 2-way sum.
    if (wk == 1) {
        #pragma unroll
        for (int st = 0; st < 2; ++st) {
            #pragma unroll
            for (int dt = 0; dt < 4; ++dt)
                #pragma unroll
                for (int j = 0; j < 4; ++j)
                    fbuf[(st * 16 + dt * 4 + j) * 256 + wq * 64 + lane] = oaccT[st][dt][j];
            lbuf[st * 256 + wq * 64 + lane] = ls[st];
        }
    }
    __syncthreads();
    // Stage D: wk=0 final sum, normalize, store.
    if (wk == 0) {
        #pragma unroll
        for (int st = 0; st < 2; ++st) {
            #pragma unroll
            for (int dt = 0; dt < 4; ++dt)
                #pragma unroll
                for (int j = 0; j < 4; ++j)
                    oaccT[st][dt][j] += fbuf[(st * 16 + dt * 4 + j) * 256 + wq * 64 + lane];
            ls[st] += lbuf[st * 256 + wq * 64 + lane];
        }
        #pragma unroll
        for (int st = 0; st < 2; ++st) {
            const float inv = 1.f / ls[st];
            const int qrow = qt * 64 + wq * 32 + st * 16 + l16;
            bf16_t* obase = Og + ((size_t)(n * SS + qrow)) * EMB + h * HS;
            #pragma unroll
            for (int dt = 0; dt < 4; ++dt) {
                bf16x4 ov;
                #pragma unroll
                for (int j = 0; j < 4; ++j) ov[j] = (bf16_t)(oaccT[st][dt][j] * inv);
                *(bf16x4*)&obase[dt * 16 + q4 * 4] = ov;
            }
        }
    }
}

// ---------------------------------------------------------------------------
// Kernel 3: out = Og @ Wout.T + bout — byte-identical to R0 (measured-best).
// ---------------------------------------------------------------------------
__global__ __launch_bounds__(512) void outproj_kernel(
    const bf16_t* __restrict__ Og, const float* __restrict__ Wout,
    const float* __restrict__ bout, float* __restrict__ out)
{
    __shared__ bf16_t As[2][128][72];
    __shared__ bf16_t Bs[2][64][72];
    const int tid = threadIdx.x;
    const int w = tid >> 6, lane = tid & 63;
    const int q4 = lane >> 4, l16 = lane & 15;
    const int wr = w >> 1, wc = w & 1;
    const int t0 = blockIdx.x * 128, c0 = blockIdx.y * 64;

    const int sr0 = tid >> 3, sc0 = (tid & 7) * 8;
    const int sr1 = sr0 + 64;
    const bf16_t* a0 = Og + (size_t)(t0 + sr0) * EMB + sc0;
    const bf16_t* a1 = Og + (size_t)(t0 + sr1) * EMB + sc0;
    const float*  b0 = Wout + (size_t)(c0 + sr0) * EMB + sc0;

    auto cvt8 = [](float4 x, float4 y) {
        bf16x8 r;
        r[0] = (bf16_t)x.x; r[1] = (bf16_t)x.y; r[2] = (bf16_t)x.z; r[3] = (bf16_t)x.w;
        r[4] = (bf16_t)y.x; r[5] = (bf16_t)y.y; r[6] = (bf16_t)y.z; r[7] = (bf16_t)y.w;
        return r;
    };

    f32x4 acc[2][2] = {};

    *(bf16x8*)&As[0][sr0][sc0] = *(const bf16x8*)a0;
    *(bf16x8*)&As[0][sr1][sc0] = *(const bf16x8*)a1;
    *(bf16x8*)&Bs[0][sr0][sc0] = cvt8(*(const float4*)b0, *(const float4*)(b0 + 4));
    __syncthreads();

    const int NE = EMB / 64;
    for (int et = 0; et < NE; ++et) {
        const int cur = et & 1;
        const bool has_next = (et + 1) < NE;
        bf16x8 ga0, ga1; float4 gb0, gb1;
        if (has_next) {
            const int e0 = (et + 1) * 64;
            ga0 = *(const bf16x8*)(a0 + e0); ga1 = *(const bf16x8*)(a1 + e0);
            gb0 = *(const float4*)(b0 + e0); gb1 = *(const float4*)(b0 + e0 + 4);
        }

        bf16x8 af[2][2], bfr[2][2];
        #pragma unroll
        for (int st = 0; st < 2; ++st)
            #pragma unroll
            for (int kk = 0; kk < 2; ++kk)
                af[st][kk] = *(const bf16x8*)&As[cur][wr * 32 + st * 16 + l16][kk * 32 + q4 * 8];
        #pragma unroll
        for (int ct = 0; ct < 2; ++ct)
            #pragma unroll
            for (int kk = 0; kk < 2; ++kk)
                bfr[ct][kk] = *(const bf16x8*)&Bs[cur][wc * 32 + ct * 16 + l16][kk * 32 + q4 * 8];
        #pragma unroll
        for (int st = 0; st < 2; ++st)
            #pragma unroll
            for (int ct = 0; ct < 2; ++ct) {
                acc[st][ct] = mfma16(af[st][0], bfr[ct][0], acc[st][ct]);
                acc[st][ct] = mfma16(af[st][1], bfr[ct][1], acc[st][ct]);
            }

        if (has_next) {
            const int nxt = 1 - cur;
            *(bf16x8*)&As[nxt][sr0][sc0] = ga0;
            *(bf16x8*)&As[nxt][sr1][sc0] = ga1;
            *(bf16x8*)&Bs[nxt][sr0][sc0] = cvt8(gb0, gb1);
        }
        __syncthreads();
    }

    #pragma unroll
    for (int ct = 0; ct < 2; ++ct) {
        const int c = c0 + wc * 32 + ct * 16 + l16;
        const float bias = bout[c];
        #pragma unroll
        for (int st = 0; st < 2; ++st)
            #pragma unroll
            for (int i = 0; i < 4; ++i)
                out[(size_t)(t0 + wr * 32 + st * 16 + q4 * 4 + i) * EMB + c]
                    = acc[st][ct][i] + bias;
    }
}

extern "C" void kernel_launch(void* const* d_in, const int* in_sizes, int n_in,
                              void* d_out, int out_size, void* d_ws, size_t ws_size,
                              hipStream_t stream)
{
    const float* values  = (const float*)d_in[0];
    const float* keys    = (const float*)d_in[1];
    const float* queries = (const float*)d_in[2];
    const int*   mask    = (const int*)d_in[3];
    const float* Wq      = (const float*)d_in[4];
    const float* Wk      = (const float*)d_in[5];
    const float* Wv      = (const float*)d_in[6];
    const float* Wout    = (const float*)d_in[7];
    const float* bout    = (const float*)d_in[8];
    float* out = (float*)d_out;

    const size_t M8 = 8ull * 1024 * 1024;
    bf16_t* Qb = (bf16_t*)d_ws;
    bf16_t* Kb = (bf16_t*)((char*)d_ws + 1 * M8);
    bf16_t* Vt = (bf16_t*)((char*)d_ws + 2 * M8);
    bf16_t* Og = (bf16_t*)((char*)d_ws + 3 * M8);

    proj_kernel<<<dim3(SS / 128, NHB, BB), 512, 0, stream>>>(
        queries, keys, values, Wq, Wk, Wv, Qb, Kb, Vt);
    attn_kernel<<<dim3(1024), 512, 0, stream>>>(
        Qb, Kb, Vt, mask, Og);
    outproj_kernel<<<dim3((BB * SS) / 128, EMB / 64), 512, 0, stream>>>(
        Og, Wout, bout, out);
}